// Round 6
// baseline (325.583 us; speedup 1.0000x reference)
//
#include <hip/hip_runtime.h>
#include <hip/hip_bf16.h>

#define D_IN 128
#define D_H  256

typedef __attribute__((ext_vector_type(8))) short short8;   // 8 bf16 (4 VGPRs)
typedef __attribute__((ext_vector_type(4))) float floatx4;  // MFMA C/D frag

__device__ __forceinline__ unsigned short f2bf(float f) {
    __hip_bfloat16 h = __float2bfloat16(f);
    return *reinterpret_cast<unsigned short*>(&h);
}
__device__ __forceinline__ float bf2f(unsigned short s) {
    union { unsigned int u; float f; } v;
    v.u = ((unsigned int)s) << 16;
    return v.f;
}

// ---------------- fused fp32 -> bf16 convert for x + all 4 weights ---------
__global__ void f2bf_all_k(const float* __restrict__ x, unsigned short* __restrict__ xb, int nx4,
                           const float* __restrict__ w1l, unsigned short* __restrict__ w1lb,
                           const float* __restrict__ w1r, unsigned short* __restrict__ w1rb, int nw14,
                           const float* __restrict__ w2l, unsigned short* __restrict__ w2lb,
                           const float* __restrict__ w2r, unsigned short* __restrict__ w2rb, int nw24) {
    int i = blockIdx.x * blockDim.x + threadIdx.x;
    const float* s; unsigned short* d; int k;
    if (i < nx4) { s = x; d = xb; k = i; }
    else {
        i -= nx4;
        if (i < nw14) { s = w1l; d = w1lb; k = i; }
        else {
            i -= nw14;
            if (i < nw14) { s = w1r; d = w1rb; k = i; }
            else {
                i -= nw14;
                if (i < nw24) { s = w2l; d = w2lb; k = i; }
                else {
                    i -= nw24;
                    if (i >= nw24) return;
                    s = w2r; d = w2rb; k = i;
                }
            }
        }
    }
    float4 v = ((const float4*)s)[k];
    ushort4 u;
    u.x = f2bf(v.x); u.y = f2bf(v.y); u.z = f2bf(v.z); u.w = f2bf(v.w);
    ((ushort4*)d)[k] = u;
}

// ---------------- CSR build ----------------
// hist also records each edge's rank within its dst bucket (atomic return),
// making scatter_k atomic-free.
__global__ void hist_k(const int* __restrict__ dst, int* __restrict__ deg,
                       int* __restrict__ rank, int E) {
    for (int e = blockIdx.x * blockDim.x + threadIdx.x; e < E; e += gridDim.x * blockDim.x)
        rank[e] = atomicAdd(&deg[dst[e]], 1);
}

__global__ __launch_bounds__(256) void scan_part_k(const int* __restrict__ deg,
                                                   int* __restrict__ bsum, int n) {
    const int b = blockIdx.x, tid = threadIdx.x;
    const int base = b * 2048;
    const int lim = min(base + 2048, n);
    int s = 0;
    for (int i = base + tid; i < lim; i += 256) s += deg[i];
    __shared__ int red[256];
    red[tid] = s; __syncthreads();
    for (int off = 128; off > 0; off >>= 1) {
        if (tid < off) red[tid] += red[tid + off];
        __syncthreads();
    }
    if (tid == 0) bsum[b] = red[0];
}

__global__ __launch_bounds__(256) void scan_final_k(const int* __restrict__ deg,
                                                    const int* __restrict__ bsum,
                                                    int* __restrict__ row_ptr,
                                                    int n, int E) {
    const int b = blockIdx.x, tid = threadIdx.x;
    const int base = b * 2048;
    __shared__ int buf[2048];
    __shared__ int ts[256];
    __shared__ int blk_prefix;
    if (tid == 0) {
        int p = 0;
        for (int i = 0; i < b; ++i) p += bsum[i];
        blk_prefix = p;
    }
    for (int i = tid; i < 2048; i += 256)
        buf[i] = (base + i < n) ? deg[base + i] : 0;
    __syncthreads();
    int local[8];
    int s = 0;
#pragma unroll
    for (int j = 0; j < 8; ++j) { local[j] = s; s += buf[tid * 8 + j]; }
    ts[tid] = s; __syncthreads();
    for (int off = 1; off < 256; off <<= 1) {
        int v = (tid >= off) ? ts[tid - off] : 0;
        __syncthreads();
        ts[tid] += v;
        __syncthreads();
    }
    const int prefix = blk_prefix + ((tid == 0) ? 0 : ts[tid - 1]);
#pragma unroll
    for (int j = 0; j < 8; ++j) {
        int idx = base + tid * 8 + j;
        if (idx < n) row_ptr[idx] = prefix + local[j];
    }
    if (b == 0 && tid == 0) row_ptr[n] = E;
}

__global__ void scatter_k(const int* __restrict__ src, const int* __restrict__ dst,
                          const int* __restrict__ rank, const int* __restrict__ row_ptr,
                          int* __restrict__ col, int E) {
    for (int e = blockIdx.x * blockDim.x + threadIdx.x; e < E; e += gridDim.x * blockDim.x)
        col[row_ptr[dst[e]] + rank[e]] = src[e];
}

// ---------------- gather-accumulate stage (shared by fused layers) ---------
template <int D, int UN>
__device__ __forceinline__ int agg_stage(const unsigned short* __restrict__ X,
                                         const int* __restrict__ col,
                                         int j, int e, int lane, float* acc) {
    constexpr int V = D / 64;
    for (; j + UN <= e; j += UN) {
        int cs[UN];
#pragma unroll
        for (int u = 0; u < UN; ++u) cs[u] = col[j + u];
        if constexpr (V == 2) {
            unsigned int vals[UN];
#pragma unroll
            for (int u = 0; u < UN; ++u)
                vals[u] = *(const unsigned int*)(X + (size_t)cs[u] * D + lane * 2);
#pragma unroll
            for (int u = 0; u < UN; ++u) {
                acc[0] += bf2f((unsigned short)(vals[u] & 0xffff));
                acc[1] += bf2f((unsigned short)(vals[u] >> 16));
            }
        } else {
            ushort4 vals[UN];
#pragma unroll
            for (int u = 0; u < UN; ++u)
                vals[u] = *(const ushort4*)(X + (size_t)cs[u] * D + lane * 4);
#pragma unroll
            for (int u = 0; u < UN; ++u) {
                acc[0] += bf2f(vals[u].x); acc[1] += bf2f(vals[u].y);
                acc[2] += bf2f(vals[u].z); acc[3] += bf2f(vals[u].w);
            }
        }
    }
    return j;
}

// ---------------- fused layer: aggregate(64 nodes)->LDS, then MFMA GEMM ----
// h[m][n] = relu( mean[m,:]@Wl[n,:] + X[m,:]@Wr[n,:] + bias[n] )
// HEAD=false: store h (bf16). HEAD=true: out[m] = dot(h[m,:], hw) + hb.
// Phase A: wave w aggregates nodes m0+w*16..+15 into sMean (bf16).
// Phase B: 64x256 GEMM; phase 0 A-frags from sMean, phase 1 A=X staged via sA.
template <int K, bool HEAD>
__global__ __launch_bounds__(256) void fused_layer_k(
    const unsigned short* __restrict__ X,   // [M][K] self features = gather source
    const int* __restrict__ col, const int* __restrict__ rp,
    const unsigned short* __restrict__ Wl, const unsigned short* __restrict__ Wr,
    const float* __restrict__ bias, unsigned short* __restrict__ Hout,
    const float* __restrict__ hw, const float* __restrict__ hb,
    float* __restrict__ out, int M) {
    constexpr int V = K / 64;
    constexpr int MSTR = K + 8;             // sMean row stride (ushorts)
    __shared__ __align__(16) unsigned short sMean[64 * MSTR];
    __shared__ __align__(16) unsigned short sA[64 * 40];
    __shared__ __align__(16) unsigned short sB[256 * 40];
    __shared__ float head_acc[64];

    const int tid = threadIdx.x;
    const int wave = tid >> 6;
    const int lane = tid & 63;
    const int c = lane & 15;
    const int q = lane >> 4;
    const int m0 = blockIdx.x * 64;

    if (HEAD && tid < 64) head_acc[tid] = 0.f;   // ordered by first k-loop barrier

    // ---- Phase A: aggregate 16 nodes per wave into sMean ----
#pragma unroll 1
    for (int i = 0; i < 16; ++i) {
        const int row = wave * 16 + i;
        int node = m0 + row;
        if (node >= M) node = M - 1;             // clamp; stores guarded later
        node = __builtin_amdgcn_readfirstlane(node);
        const int s = rp[node], e = rp[node + 1];
        float acc[V] = {0.f};
        int j = s;
        j = agg_stage<K, 8>(X, col, j, e, lane, acc);
        j = agg_stage<K, 4>(X, col, j, e, lane, acc);
        j = agg_stage<K, 2>(X, col, j, e, lane, acc);
        j = agg_stage<K, 1>(X, col, j, e, lane, acc);
        const float inv = 1.f / fmaxf((float)(e - s), 1.f);
        if constexpr (V == 2) {
            ushort2 o;
            o.x = f2bf(acc[0] * inv); o.y = f2bf(acc[1] * inv);
            *(ushort2*)&sMean[row * MSTR + lane * 2] = o;
        } else {
            ushort4 o;
            o.x = f2bf(acc[0] * inv); o.y = f2bf(acc[1] * inv);
            o.z = f2bf(acc[2] * inv); o.w = f2bf(acc[3] * inv);
            *(ushort4*)&sMean[row * MSTR + lane * 4] = o;
        }
    }

    // ---- Phase B: GEMM ----
    floatx4 acc[4][4];
#pragma unroll
    for (int mi = 0; mi < 4; ++mi)
#pragma unroll
        for (int ni = 0; ni < 4; ++ni) acc[mi][ni] = (floatx4){0.f, 0.f, 0.f, 0.f};

    const int arow = tid >> 2;
    const int aseg = (tid & 3) * 8;
    int gr = m0 + arow;
    if (gr >= M) gr = M - 1;

    for (int phase = 0; phase < 2; ++phase) {
        const unsigned short* Wp = phase ? Wr : Wl;
        for (int k0 = 0; k0 < K; k0 += 32) {
            short8 va;
            if (phase) va = *(const short8*)(X + (size_t)gr * K + k0 + aseg);
            short8 vb[4];
#pragma unroll
            for (int i = 0; i < 4; ++i) {
                int brow = arow + i * 64;
                vb[i] = *(const short8*)(Wp + (size_t)brow * K + k0 + aseg);
            }
            __syncthreads();   // orders Phase-A sMean writes / prev-iter LDS reads
            if (phase) *(short8*)&sA[arow * 40 + aseg] = va;
#pragma unroll
            for (int i = 0; i < 4; ++i)
                *(short8*)&sB[(arow + i * 64) * 40 + aseg] = vb[i];
            __syncthreads();

            const unsigned short* Ab = phase ? sA : (const unsigned short*)&sMean[k0];
            const int astr = phase ? 40 : MSTR;
            short8 af[4], bf[4];
#pragma unroll
            for (int mi = 0; mi < 4; ++mi)
                af[mi] = *(const short8*)&Ab[(mi * 16 + c) * astr + q * 8];
#pragma unroll
            for (int ni = 0; ni < 4; ++ni)
                bf[ni] = *(const short8*)&sB[(wave * 64 + ni * 16 + c) * 40 + q * 8];
#pragma unroll
            for (int mi = 0; mi < 4; ++mi)
#pragma unroll
                for (int ni = 0; ni < 4; ++ni)
                    acc[mi][ni] = __builtin_amdgcn_mfma_f32_16x16x32_bf16(
                        af[mi], bf[ni], acc[mi][ni], 0, 0, 0);
        }
    }

    if (!HEAD) {
#pragma unroll
        for (int mi = 0; mi < 4; ++mi)
#pragma unroll
            for (int ni = 0; ni < 4; ++ni) {
                const int n = wave * 64 + ni * 16 + c;
                const float bv = bias[n];
#pragma unroll
                for (int reg = 0; reg < 4; ++reg) {
                    const int m = m0 + mi * 16 + q * 4 + reg;
                    if (m < M) {
                        float v = fmaxf(acc[mi][ni][reg] + bv, 0.f);
                        Hout[(size_t)m * 256 + n] = f2bf(v);
                    }
                }
            }
    } else {
#pragma unroll
        for (int mi = 0; mi < 4; ++mi) {
            float p[4] = {0.f, 0.f, 0.f, 0.f};
#pragma unroll
            for (int ni = 0; ni < 4; ++ni) {
                const int n = wave * 64 + ni * 16 + c;
                const float bv = bias[n];
                const float hv = hw[n];
#pragma unroll
                for (int reg = 0; reg < 4; ++reg)
                    p[reg] += fmaxf(acc[mi][ni][reg] + bv, 0.f) * hv;
            }
#pragma unroll
            for (int reg = 0; reg < 4; ++reg) {
                float v = p[reg];
                v += __shfl_xor(v, 1, 64);
                v += __shfl_xor(v, 2, 64);
                v += __shfl_xor(v, 4, 64);
                v += __shfl_xor(v, 8, 64);
                if (c == 0) atomicAdd(&head_acc[mi * 16 + q * 4 + reg], v);
            }
        }
        __syncthreads();
        if (tid < 64) {
            const int m = m0 + tid;
            if (m < M) out[m] = head_acc[tid] + hb[0];
        }
    }
}

// ---------------- launch ----------------
extern "C" void kernel_launch(void* const* d_in, const int* in_sizes, int n_in,
                              void* d_out, int out_size, void* d_ws, size_t ws_size,
                              hipStream_t stream) {
    const float* x    = (const float*)d_in[0];
    const int*   ei   = (const int*)d_in[1];
    const float* W1l  = (const float*)d_in[2];
    const float* b1   = (const float*)d_in[3];
    const float* W1r  = (const float*)d_in[4];
    const float* W2l  = (const float*)d_in[5];
    const float* b2   = (const float*)d_in[6];
    const float* W2r  = (const float*)d_in[7];
    const float* hw   = (const float*)d_in[8];
    const float* hb   = (const float*)d_in[9];
    float* out = (float*)d_out;

    const int M = in_sizes[0] / D_IN;       // 50000
    const int E = in_sizes[1] / 2;          // 800000
    const int* src = ei;
    const int* dst = ei + E;

    size_t off = 0;
    auto alloc = [&](size_t bytes) -> void* {
        void* p = (char*)d_ws + off;
        off += (bytes + 255) & ~(size_t)255;
        return p;
    };
    int* deg  = (int*)alloc((size_t)M * 4);
    int* rp   = (int*)alloc((size_t)(M + 1) * 4);
    int* bsum = (int*)alloc(256 * 4);
    int* rank = (int*)alloc((size_t)E * 4);
    int* col  = (int*)alloc((size_t)E * 4);
    unsigned short* xb   = (unsigned short*)alloc((size_t)M * D_IN * 2);
    unsigned short* w1lb = (unsigned short*)alloc((size_t)D_H * D_IN * 2);
    unsigned short* w1rb = (unsigned short*)alloc((size_t)D_H * D_IN * 2);
    unsigned short* w2lb = (unsigned short*)alloc((size_t)D_H * D_H * 2);
    unsigned short* w2rb = (unsigned short*)alloc((size_t)D_H * D_H * 2);
    unsigned short* h1   = (unsigned short*)alloc((size_t)M * D_H * 2);

    hipMemsetAsync(deg, 0, (size_t)M * 4, stream);

    // CSR (scatter is atomic-free: rank captured in hist)
    const int nseg = (M + 2047) / 2048;     // 25
    hist_k<<<512, 256, 0, stream>>>(dst, deg, rank, E);
    scan_part_k<<<nseg, 256, 0, stream>>>(deg, bsum, M);
    scan_final_k<<<nseg, 256, 0, stream>>>(deg, bsum, rp, M, E);
    scatter_k<<<512, 256, 0, stream>>>(src, dst, rank, rp, col, E);

    // bf16 conversions (x + all weights, one dispatch)
    {
        const int nx4 = (M * D_IN) / 4;
        const int nw14 = (D_H * D_IN) / 4;
        const int nw24 = (D_H * D_H) / 4;
        const int tot = nx4 + 2 * nw14 + 2 * nw24;
        f2bf_all_k<<<(tot + 255) / 256, 256, 0, stream>>>(
            x, xb, nx4, W1l, w1lb, W1r, w1rb, nw14, W2l, w2lb, W2r, w2rb, nw24);
    }

    const int nblk = (M + 63) / 64;

    // layer 1 (fused aggregate + GEMM)
    fused_layer_k<D_IN, false><<<nblk, 256, 0, stream>>>(
        xb, col, rp, w1lb, w1rb, b1, h1, nullptr, nullptr, nullptr, M);

    // layer 2 + head (fused aggregate + GEMM + head)
    fused_layer_k<D_H, true><<<nblk, 256, 0, stream>>>(
        h1, col, rp, w2lb, w2rb, b2, nullptr, hw, hb, out, M);
}

// Round 7
// 270.175 us; speedup vs baseline: 1.2051x; 1.2051x over previous
//
#include <hip/hip_runtime.h>
#include <hip/hip_bf16.h>

#define D_IN 128
#define D_H  256

typedef __attribute__((ext_vector_type(8))) short short8;   // 8 bf16 (4 VGPRs)
typedef __attribute__((ext_vector_type(4))) float floatx4;  // MFMA C/D frag

__device__ __forceinline__ unsigned short f2bf(float f) {
    __hip_bfloat16 h = __float2bfloat16(f);
    return *reinterpret_cast<unsigned short*>(&h);
}
__device__ __forceinline__ float bf2f(unsigned short s) {
    union { unsigned int u; float f; } v;
    v.u = ((unsigned int)s) << 16;
    return v.f;
}

// ------------- fused: histogram (+rank) AND fp32->bf16 conversions ---------
// blocks [0,512): edge histogram; blocks [512,...): vectorized cast of x + weights
__global__ void hist_conv_k(const int* __restrict__ dst, int* __restrict__ deg,
                            int* __restrict__ rank, int E,
                            const float* __restrict__ x, unsigned short* __restrict__ xb, int nx4,
                            const float* __restrict__ w1l, unsigned short* __restrict__ w1lb,
                            const float* __restrict__ w1r, unsigned short* __restrict__ w1rb, int nw14,
                            const float* __restrict__ w2l, unsigned short* __restrict__ w2lb,
                            const float* __restrict__ w2r, unsigned short* __restrict__ w2rb, int nw24) {
    if (blockIdx.x < 512) {
        for (int e = blockIdx.x * 256 + threadIdx.x; e < E; e += 512 * 256)
            rank[e] = atomicAdd(&deg[dst[e]], 1);
        return;
    }
    int i = (blockIdx.x - 512) * 256 + threadIdx.x;
    const float* s; unsigned short* d; int k;
    if (i < nx4) { s = x; d = xb; k = i; }
    else {
        i -= nx4;
        if (i < nw14) { s = w1l; d = w1lb; k = i; }
        else {
            i -= nw14;
            if (i < nw14) { s = w1r; d = w1rb; k = i; }
            else {
                i -= nw14;
                if (i < nw24) { s = w2l; d = w2lb; k = i; }
                else {
                    i -= nw24;
                    if (i >= nw24) return;
                    s = w2r; d = w2rb; k = i;
                }
            }
        }
    }
    float4 v = ((const float4*)s)[k];
    ushort4 u;
    u.x = f2bf(v.x); u.y = f2bf(v.y); u.z = f2bf(v.z); u.w = f2bf(v.w);
    ((ushort4*)d)[k] = u;
}

__global__ __launch_bounds__(256) void scan_part_k(const int* __restrict__ deg,
                                                   int* __restrict__ bsum, int n) {
    const int b = blockIdx.x, tid = threadIdx.x;
    const int base = b * 2048;
    const int lim = min(base + 2048, n);
    int s = 0;
    for (int i = base + tid; i < lim; i += 256) s += deg[i];
    __shared__ int red[256];
    red[tid] = s; __syncthreads();
    for (int off = 128; off > 0; off >>= 1) {
        if (tid < off) red[tid] += red[tid + off];
        __syncthreads();
    }
    if (tid == 0) bsum[b] = red[0];
}

__global__ __launch_bounds__(256) void scan_final_k(const int* __restrict__ deg,
                                                    const int* __restrict__ bsum,
                                                    int* __restrict__ row_ptr,
                                                    int n, int E) {
    const int b = blockIdx.x, tid = threadIdx.x;
    const int base = b * 2048;
    __shared__ int buf[2048];
    __shared__ int ts[256];
    __shared__ int blk_prefix;
    if (tid == 0) {
        int p = 0;
        for (int i = 0; i < b; ++i) p += bsum[i];
        blk_prefix = p;
    }
    for (int i = tid; i < 2048; i += 256)
        buf[i] = (base + i < n) ? deg[base + i] : 0;
    __syncthreads();
    int local[8];
    int s = 0;
#pragma unroll
    for (int j = 0; j < 8; ++j) { local[j] = s; s += buf[tid * 8 + j]; }
    ts[tid] = s; __syncthreads();
    for (int off = 1; off < 256; off <<= 1) {
        int v = (tid >= off) ? ts[tid - off] : 0;
        __syncthreads();
        ts[tid] += v;
        __syncthreads();
    }
    const int prefix = blk_prefix + ((tid == 0) ? 0 : ts[tid - 1]);
#pragma unroll
    for (int j = 0; j < 8; ++j) {
        int idx = base + tid * 8 + j;
        if (idx < n) row_ptr[idx] = prefix + local[j];
    }
    if (b == 0 && tid == 0) row_ptr[n] = E;
}

__global__ void scatter_k(const int* __restrict__ src, const int* __restrict__ dst,
                          const int* __restrict__ rank, const int* __restrict__ row_ptr,
                          int* __restrict__ col, int E) {
    for (int e = blockIdx.x * blockDim.x + threadIdx.x; e < E; e += gridDim.x * blockDim.x)
        col[row_ptr[dst[e]] + rank[e]] = src[e];
}

// ---------------- mean aggregation v3 (unchanged from R5) ----------
template <int D, int UN>
__device__ __forceinline__ int agg_stage(const unsigned short* __restrict__ X,
                                         const int* __restrict__ col,
                                         int j, int e, int lane, float* acc) {
    constexpr int V = D / 64;
    for (; j + UN <= e; j += UN) {
        int cs[UN];
#pragma unroll
        for (int u = 0; u < UN; ++u) cs[u] = col[j + u];
        if constexpr (V == 2) {
            unsigned int vals[UN];
#pragma unroll
            for (int u = 0; u < UN; ++u)
                vals[u] = *(const unsigned int*)(X + (size_t)cs[u] * D + lane * 2);
#pragma unroll
            for (int u = 0; u < UN; ++u) {
                acc[0] += bf2f((unsigned short)(vals[u] & 0xffff));
                acc[1] += bf2f((unsigned short)(vals[u] >> 16));
            }
        } else {
            ushort4 vals[UN];
#pragma unroll
            for (int u = 0; u < UN; ++u)
                vals[u] = *(const ushort4*)(X + (size_t)cs[u] * D + lane * 4);
#pragma unroll
            for (int u = 0; u < UN; ++u) {
                acc[0] += bf2f(vals[u].x); acc[1] += bf2f(vals[u].y);
                acc[2] += bf2f(vals[u].z); acc[3] += bf2f(vals[u].w);
            }
        }
    }
    return j;
}

template <int D>
__global__ __launch_bounds__(256) void aggregate_v3(
    const unsigned short* __restrict__ X, const int* __restrict__ col,
    const int* __restrict__ rp, unsigned short* __restrict__ out, int Mnodes) {
    int node = __builtin_amdgcn_readfirstlane((blockIdx.x << 2) + (threadIdx.x >> 6));
    if (node >= Mnodes) return;
    const int lane = threadIdx.x & 63;
    const int s = rp[node], e = rp[node + 1];
    constexpr int V = D / 64;
    float acc[V] = {0.f};

    int j = s;
    j = agg_stage<D, 8>(X, col, j, e, lane, acc);
    j = agg_stage<D, 4>(X, col, j, e, lane, acc);
    j = agg_stage<D, 2>(X, col, j, e, lane, acc);
    j = agg_stage<D, 1>(X, col, j, e, lane, acc);

    const float inv = 1.f / fmaxf((float)(e - s), 1.f);
    if constexpr (V == 2) {
        ushort2 o;
        o.x = f2bf(acc[0] * inv); o.y = f2bf(acc[1] * inv);
        *(ushort2*)(out + (size_t)node * D + lane * 2) = o;
    } else {
        ushort4 o;
        o.x = f2bf(acc[0] * inv); o.y = f2bf(acc[1] * inv);
        o.z = f2bf(acc[2] * inv); o.w = f2bf(acc[3] * inv);
        *(ushort4*)(out + (size_t)node * D + lane * 4) = o;
    }
}

// ---------------- dual-input bf16 MFMA GEMM, block tile 128 x 256 ----------
// out[m][n] = relu( A1[m,:]@W1[n,:] + A2[m,:]@W2[n,:] + bias[n] )
// 256 threads / 4 waves; wave w owns N-strip w*64..+64; 8x4 16x16 tiles/wave.
template <int K, bool HEAD>
__global__ __launch_bounds__(256, 2) void gemm_mfma_k(
    const unsigned short* __restrict__ A1, const unsigned short* __restrict__ W1,
    const unsigned short* __restrict__ A2, const unsigned short* __restrict__ W2,
    const float* __restrict__ bias, unsigned short* __restrict__ Hout,
    const float* __restrict__ hw, const float* __restrict__ hb,
    float* __restrict__ out, int M) {
    __shared__ __align__(16) unsigned short sA[128 * 40];
    __shared__ __align__(16) unsigned short sB[256 * 40];
    __shared__ float head_acc[128];

    const int tid = threadIdx.x;
    const int wave = tid >> 6;
    const int lane = tid & 63;
    const int c = lane & 15;
    const int q = lane >> 4;
    const int m0 = blockIdx.x * 128;

    if (HEAD && tid < 128) head_acc[tid] = 0.f;  // ordered by first k-loop barrier

    floatx4 acc[8][4];
#pragma unroll
    for (int mi = 0; mi < 8; ++mi)
#pragma unroll
        for (int ni = 0; ni < 4; ++ni) acc[mi][ni] = (floatx4){0.f, 0.f, 0.f, 0.f};

    // staging: A rows 0..127, thread loads 2x short8; B rows 0..255 via 4x short8
    const int arow = tid >> 1;          // 0..127
    const int aseg = (tid & 1) * 16;    // 0 or 16 (ushorts)
    const int brow = tid >> 2;          // 0..63
    const int bseg = (tid & 3) * 8;
    int gr = m0 + arow;
    if (gr >= M) gr = M - 1;            // clamp; stores guarded

    for (int phase = 0; phase < 2; ++phase) {
        const unsigned short* Ap = phase ? A2 : A1;
        const unsigned short* Wp = phase ? W2 : W1;
        for (int k0 = 0; k0 < K; k0 += 32) {
            short8 va0 = *(const short8*)(Ap + (size_t)gr * K + k0 + aseg);
            short8 va1 = *(const short8*)(Ap + (size_t)gr * K + k0 + aseg + 8);
            short8 vb[4];
#pragma unroll
            for (int i = 0; i < 4; ++i)
                vb[i] = *(const short8*)(Wp + (size_t)(brow + i * 64) * K + k0 + bseg);
            __syncthreads();            // prev iteration's LDS reads done
            *(short8*)&sA[arow * 40 + aseg] = va0;
            *(short8*)&sA[arow * 40 + aseg + 8] = va1;
#pragma unroll
            for (int i = 0; i < 4; ++i)
                *(short8*)&sB[(brow + i * 64) * 40 + bseg] = vb[i];
            __syncthreads();

            short8 af[8], bf[4];
#pragma unroll
            for (int mi = 0; mi < 8; ++mi)
                af[mi] = *(const short8*)&sA[(mi * 16 + c) * 40 + q * 8];
#pragma unroll
            for (int ni = 0; ni < 4; ++ni)
                bf[ni] = *(const short8*)&sB[(wave * 64 + ni * 16 + c) * 40 + q * 8];
#pragma unroll
            for (int mi = 0; mi < 8; ++mi)
#pragma unroll
                for (int ni = 0; ni < 4; ++ni)
                    acc[mi][ni] = __builtin_amdgcn_mfma_f32_16x16x32_bf16(
                        af[mi], bf[ni], acc[mi][ni], 0, 0, 0);
        }
    }

    if (!HEAD) {
#pragma unroll
        for (int mi = 0; mi < 8; ++mi)
#pragma unroll
            for (int ni = 0; ni < 4; ++ni) {
                const int n = wave * 64 + ni * 16 + c;
                const float bv = bias[n];
#pragma unroll
                for (int reg = 0; reg < 4; ++reg) {
                    const int m = m0 + mi * 16 + q * 4 + reg;
                    if (m < M) {
                        float v = fmaxf(acc[mi][ni][reg] + bv, 0.f);
                        Hout[(size_t)m * 256 + n] = f2bf(v);
                    }
                }
            }
    } else {
#pragma unroll
        for (int mi = 0; mi < 8; ++mi) {
            float p[4] = {0.f, 0.f, 0.f, 0.f};
#pragma unroll
            for (int ni = 0; ni < 4; ++ni) {
                const int n = wave * 64 + ni * 16 + c;
                const float bv = bias[n];
                const float hv = hw[n];
#pragma unroll
                for (int reg = 0; reg < 4; ++reg)
                    p[reg] += fmaxf(acc[mi][ni][reg] + bv, 0.f) * hv;
            }
#pragma unroll
            for (int reg = 0; reg < 4; ++reg) {
                float v = p[reg];
                v += __shfl_xor(v, 1, 64);
                v += __shfl_xor(v, 2, 64);
                v += __shfl_xor(v, 4, 64);
                v += __shfl_xor(v, 8, 64);
                if (c == 0) atomicAdd(&head_acc[mi * 16 + q * 4 + reg], v);
            }
        }
        __syncthreads();
        if (tid < 128) {
            const int m = m0 + tid;
            if (m < M) out[m] = head_acc[tid] + hb[0];
        }
    }
}

// ---------------- launch ----------------
extern "C" void kernel_launch(void* const* d_in, const int* in_sizes, int n_in,
                              void* d_out, int out_size, void* d_ws, size_t ws_size,
                              hipStream_t stream) {
    const float* x    = (const float*)d_in[0];
    const int*   ei   = (const int*)d_in[1];
    const float* W1l  = (const float*)d_in[2];
    const float* b1   = (const float*)d_in[3];
    const float* W1r  = (const float*)d_in[4];
    const float* W2l  = (const float*)d_in[5];
    const float* b2   = (const float*)d_in[6];
    const float* W2r  = (const float*)d_in[7];
    const float* hw   = (const float*)d_in[8];
    const float* hb   = (const float*)d_in[9];
    float* out = (float*)d_out;

    const int M = in_sizes[0] / D_IN;       // 50000
    const int E = in_sizes[1] / 2;          // 800000
    const int* src = ei;
    const int* dst = ei + E;

    size_t off = 0;
    auto alloc = [&](size_t bytes) -> void* {
        void* p = (char*)d_ws + off;
        off += (bytes + 255) & ~(size_t)255;
        return p;
    };
    int* deg  = (int*)alloc((size_t)M * 4);
    int* rp   = (int*)alloc((size_t)(M + 1) * 4);
    int* bsum = (int*)alloc(256 * 4);
    int* rank = (int*)alloc((size_t)E * 4);
    int* col  = (int*)alloc((size_t)E * 4);
    unsigned short* xb    = (unsigned short*)alloc((size_t)M * D_IN * 2);
    unsigned short* w1lb  = (unsigned short*)alloc((size_t)D_H * D_IN * 2);
    unsigned short* w1rb  = (unsigned short*)alloc((size_t)D_H * D_IN * 2);
    unsigned short* w2lb  = (unsigned short*)alloc((size_t)D_H * D_H * 2);
    unsigned short* w2rb  = (unsigned short*)alloc((size_t)D_H * D_H * 2);
    unsigned short* mean1 = (unsigned short*)alloc((size_t)M * D_IN * 2);
    unsigned short* h1    = (unsigned short*)alloc((size_t)M * D_H * 2);
    unsigned short* mean2 = (unsigned short*)alloc((size_t)M * D_H * 2);

    hipMemsetAsync(deg, 0, (size_t)M * 4, stream);

    // fused histogram + conversions
    const int nx4 = (M * D_IN) / 4;
    const int nw14 = (D_H * D_IN) / 4;
    const int nw24 = (D_H * D_H) / 4;
    const int tot4 = nx4 + 2 * nw14 + 2 * nw24;
    const int convblk = (tot4 + 255) / 256;
    hist_conv_k<<<512 + convblk, 256, 0, stream>>>(
        dst, deg, rank, E,
        x, xb, nx4, W1l, w1lb, W1r, w1rb, nw14, W2l, w2lb, W2r, w2rb, nw24);

    // scan + scatter
    const int nseg = (M + 2047) / 2048;     // 25
    scan_part_k<<<nseg, 256, 0, stream>>>(deg, bsum, M);
    scan_final_k<<<nseg, 256, 0, stream>>>(deg, bsum, rp, M, E);
    scatter_k<<<512, 256, 0, stream>>>(src, dst, rank, rp, col, E);

    const int nblk = (M + 127) / 128;
    const int ablk = (M + 3) / 4;

    // layer 1
    aggregate_v3<D_IN><<<ablk, 256, 0, stream>>>(xb, col, rp, mean1, M);
    gemm_mfma_k<D_IN, false><<<nblk, 256, 0, stream>>>(
        mean1, w1lb, xb, w1rb, b1, h1, nullptr, nullptr, nullptr, M);

    // layer 2 + fused head
    aggregate_v3<D_H><<<ablk, 256, 0, stream>>>(h1, col, rp, mean2, M);
    gemm_mfma_k<D_H, true><<<nblk, 256, 0, stream>>>(
        mean2, w2lb, h1, w2rb, b2, nullptr, hw, hb, out, M);
}